// Round 1
// baseline (725.150 us; speedup 1.0000x reference)
//
#include <hip/hip_runtime.h>
#include <hip/hip_fp16.h>

typedef _Float16 half8 __attribute__((ext_vector_type(8)));
typedef _Float16 half4 __attribute__((ext_vector_type(4)));
typedef float floatx4 __attribute__((ext_vector_type(4)));

// async global->LDS, 16B per lane; LDS dest is wave-uniform base + lane*16
#define GLDS16(g, l)                                                           \
  __builtin_amdgcn_global_load_lds(                                            \
      (const __attribute__((address_space(1))) void*)(g),                      \
      (__attribute__((address_space(3))) void*)(l), 16, 0, 0)

// ---------------------------------------------------------------------------
// Effective-weight prep: W_eff = sum_k mw[k]*(mu[k] + exp(0.5*lv[k])*n[k])
// ---------------------------------------------------------------------------
__device__ inline void mix_coeffs(const float* lv, const float* ml,
                                  float* cmu, float* cn) {
  float m0 = ml[0], m1 = ml[1], m2 = ml[2], m3 = ml[3];
  float mx = fmaxf(fmaxf(m0, m1), fmaxf(m2, m3));
  float e0 = __expf(m0 - mx), e1 = __expf(m1 - mx);
  float e2 = __expf(m2 - mx), e3 = __expf(m3 - mx);
  float inv = 1.0f / (e0 + e1 + e2 + e3);
  cmu[0] = e0 * inv; cmu[1] = e1 * inv; cmu[2] = e2 * inv; cmu[3] = e3 * inv;
  cn[0] = cmu[0] * __expf(0.5f * lv[0]);
  cn[1] = cmu[1] * __expf(0.5f * lv[1]);
  cn[2] = cmu[2] * __expf(0.5f * lv[2]);
  cn[3] = cmu[3] * __expf(0.5f * lv[3]);
}

__global__ __launch_bounds__(256) void prep_w(
    const float* __restrict__ mu, const float* __restrict__ nz,
    const float* __restrict__ lv, const float* __restrict__ ml,
    _Float16* __restrict__ out, int count) {
  float cmu[4], cn[4];
  mix_coeffs(lv, ml, cmu, cn);
  long i = ((long)blockIdx.x * 256 + threadIdx.x) * 4;
  if (i >= count) return;
  float rx = 0.f, ry = 0.f, rz = 0.f, rw = 0.f;
#pragma unroll
  for (int k = 0; k < 4; ++k) {
    float4 a = *(const float4*)(mu + (long)k * count + i);
    float4 b = *(const float4*)(nz + (long)k * count + i);
    rx += cmu[k] * a.x + cn[k] * b.x;
    ry += cmu[k] * a.y + cn[k] * b.y;
    rz += cmu[k] * a.z + cn[k] * b.z;
    rw += cmu[k] * a.w + cn[k] * b.w;
  }
  half4 h = {(_Float16)rx, (_Float16)ry, (_Float16)rz, (_Float16)rw};
  *(half4*)(out + i) = h;
}

__global__ __launch_bounds__(256) void prep_b(
    const float* __restrict__ bmu, const float* __restrict__ bn,
    const float* __restrict__ lv, const float* __restrict__ ml,
    float* __restrict__ out, int O) {
  float cmu[4], cn[4];
  mix_coeffs(lv, ml, cmu, cn);
  int i = blockIdx.x * 256 + threadIdx.x;
  if (i >= O) return;
  float r = 0.f;
#pragma unroll
  for (int k = 0; k < 4; ++k)
    r += cmu[k] * bmu[k * O + i] + cn[k] * bn[k * O + i];
  out[i] = r;
}

__global__ __launch_bounds__(256) void cvt_half(
    const float* __restrict__ in, _Float16* __restrict__ out) {
  long i = ((long)blockIdx.x * 256 + threadIdx.x) * 4;
  float4 v = *(const float4*)(in + i);
  half4 h = {(_Float16)v.x, (_Float16)v.y, (_Float16)v.z, (_Float16)v.w};
  *(half4*)(out + i) = h;
}

// ---------------------------------------------------------------------------
// GEMM: C[M,N] = act(A[M,K] * B[N,K]^T + bias), A/B fp16, 128x128 tile, BK=64
// 4 waves in 2x2, each wave 4x4 grid of 16x16x32 fp16 MFMA tiles.
// LDS holds tiles in fragment order: granule(mt 0..7, q 0..7, m 0..15) of 8
// fp16 at byte offset ((mt*8+q)*16+m)*16, so compute-phase ds_read is
// lane-linear (base + lane*16): conflict-free b128 reads, no repack.
// ---------------------------------------------------------------------------
template <bool RELU, bool OUT_HALF>
__global__ __launch_bounds__(256) void gemm_nt(
    const _Float16* __restrict__ A, const _Float16* __restrict__ B,
    const float* __restrict__ bias, void* __restrict__ Cout,
    int M, int N, int K) {
  __shared__ _Float16 sA[128 * 64];
  __shared__ _Float16 sB[128 * 64];

  const int t = threadIdx.x;
  const int l = t & 63;
  const int w = t >> 6;
  const int wr = w >> 1;   // wave row 0..1 (64 rows each)
  const int wc = w & 1;    // wave col 0..1
  const long rowBlock = (long)blockIdx.x * 128;
  const long colBlock = (long)blockIdx.y * 128;

  floatx4 acc[4][4] = {};

  // per-thread staging source pointers (4 granules for A, 4 for B)
  const _Float16* ga[4];
  const _Float16* gb[4];
#pragma unroll
  for (int j = 0; j < 4; ++j) {
    int s = j * 256 + t;          // granule slot 0..1023
    int mt = s >> 7;              // 16-row tile 0..7
    int q = (s >> 4) & 7;         // k-granule (8 fp16) 0..7
    int m = s & 15;               // row within tile
    ga[j] = A + (rowBlock + mt * 16 + m) * (long)K + q * 8;
    gb[j] = B + (colBlock + mt * 16 + m) * (long)K + q * 8;
  }
  char* sAw = (char*)sA + w * 64 * 16;  // wave-uniform LDS staging base
  char* sBw = (char*)sB + w * 64 * 16;

  for (int k0 = 0; k0 < K; k0 += 64) {
#pragma unroll
    for (int j = 0; j < 4; ++j) {
      GLDS16(ga[j] + k0, sAw + j * 4096);
      GLDS16(gb[j] + k0, sBw + j * 4096);
    }
    __syncthreads();  // drains vmcnt (compiler emits waitcnt before barrier)
#pragma unroll
    for (int s = 0; s < 2; ++s) {  // two K=32 MFMA steps per BK=64
      half8 af[4], bf[4];
#pragma unroll
      for (int r = 0; r < 4; ++r)
        af[r] = *(const half8*)((const char*)sA +
                                ((wr * 4 + r) * 2048 + s * 1024 + l * 16));
#pragma unroll
      for (int c = 0; c < 4; ++c)
        bf[c] = *(const half8*)((const char*)sB +
                                ((wc * 4 + c) * 2048 + s * 1024 + l * 16));
#pragma unroll
      for (int r = 0; r < 4; ++r)
#pragma unroll
        for (int c = 0; c < 4; ++c)
          acc[r][c] = __builtin_amdgcn_mfma_f32_16x16x32_f16(
              af[r], bf[c], acc[r][c], 0, 0, 0);
    }
    __syncthreads();
  }

  // epilogue: C/D layout col=lane&15, row=(lane>>4)*4+reg
  const long row0 = rowBlock + wr * 64 + (l >> 4) * 4;
  const long col0 = colBlock + wc * 64 + (l & 15);
  float bv[4];
#pragma unroll
  for (int c = 0; c < 4; ++c) bv[c] = bias[col0 + c * 16];
#pragma unroll
  for (int r = 0; r < 4; ++r) {
#pragma unroll
    for (int c = 0; c < 4; ++c) {
#pragma unroll
      for (int e = 0; e < 4; ++e) {
        float v = acc[r][c][e] + bv[c];
        if (RELU) v = fmaxf(v, 0.0f);
        long row = row0 + r * 16 + e;
        long col = col0 + c * 16;
        if (OUT_HALF)
          ((_Float16*)Cout)[row * N + col] = (_Float16)v;
        else
          ((float*)Cout)[row * N + col] = v;
      }
    }
  }
}

// ---------------------------------------------------------------------------
// Row softmax over N=1024, one block per row, one float4 per thread
// ---------------------------------------------------------------------------
__global__ __launch_bounds__(256) void softmax_rows(float* __restrict__ io) {
  const int N = 1024;
  float* p = io + (long)blockIdx.x * N;
  int t = threadIdx.x;
  int w = t >> 6;
  float4 v = ((const float4*)p)[t];
  float m = fmaxf(fmaxf(v.x, v.y), fmaxf(v.z, v.w));
#pragma unroll
  for (int off = 32; off > 0; off >>= 1) m = fmaxf(m, __shfl_xor(m, off));
  __shared__ float red[8];
  if ((t & 63) == 0) red[w] = m;
  __syncthreads();
  m = fmaxf(fmaxf(red[0], red[1]), fmaxf(red[2], red[3]));
  float4 e;
  e.x = __expf(v.x - m); e.y = __expf(v.y - m);
  e.z = __expf(v.z - m); e.w = __expf(v.w - m);
  float s = e.x + e.y + e.z + e.w;
#pragma unroll
  for (int off = 32; off > 0; off >>= 1) s += __shfl_xor(s, off);
  if ((t & 63) == 0) red[4 + w] = s;
  __syncthreads();
  s = red[4] + red[5] + red[6] + red[7];
  float inv = 1.0f / s;
  float4 o = {e.x * inv, e.y * inv, e.z * inv, e.w * inv};
  ((float4*)p)[t] = o;
}

// ---------------------------------------------------------------------------
extern "C" void kernel_launch(void* const* d_in, const int* in_sizes, int n_in,
                              void* d_out, int out_size, void* d_ws,
                              size_t ws_size, hipStream_t stream) {
  const float* x     = (const float*)d_in[0];
  const float* w_mu0 = (const float*)d_in[1];
  const float* b_mu0 = (const float*)d_in[2];
  const float* w_lv0 = (const float*)d_in[3];
  const float* b_lv0 = (const float*)d_in[4];
  const float* ml0   = (const float*)d_in[5];
  const float* w_n0  = (const float*)d_in[6];
  const float* b_n0  = (const float*)d_in[7];
  const float* w_mu1 = (const float*)d_in[8];
  const float* b_mu1 = (const float*)d_in[9];
  const float* w_lv1 = (const float*)d_in[10];
  const float* b_lv1 = (const float*)d_in[11];
  const float* ml1   = (const float*)d_in[12];
  const float* w_n1  = (const float*)d_in[13];
  const float* b_n1  = (const float*)d_in[14];
  const float* w_mu2 = (const float*)d_in[15];
  const float* b_mu2 = (const float*)d_in[16];
  const float* w_lv2 = (const float*)d_in[17];
  const float* b_lv2 = (const float*)d_in[18];
  const float* ml2   = (const float*)d_in[19];
  const float* w_n2  = (const float*)d_in[20];
  const float* b_n2  = (const float*)d_in[21];

  char* ws = (char*)d_ws;
  _Float16* x16 = (_Float16*)(ws);              // 33,554,432 B (reused as h1)
  _Float16* h0  = (_Float16*)(ws + 33554432);   // 33,554,432 B
  _Float16* W0  = (_Float16*)(ws + 67108864);   //  8,388,608 B
  _Float16* W1  = (_Float16*)(ws + 75497472);   //  8,388,608 B
  _Float16* W2  = (_Float16*)(ws + 83886080);   //  4,194,304 B
  float* b0 = (float*)(ws + 88080384);          //  8 KB
  float* b1 = (float*)(ws + 88088576);          //  8 KB
  float* b2 = (float*)(ws + 88096768);          //  4 KB

  prep_w<<<4096, 256, 0, stream>>>(w_mu0, w_n0, w_lv0, ml0, W0, 2048 * 2048);
  prep_w<<<4096, 256, 0, stream>>>(w_mu1, w_n1, w_lv1, ml1, W1, 2048 * 2048);
  prep_w<<<2048, 256, 0, stream>>>(w_mu2, w_n2, w_lv2, ml2, W2, 1024 * 2048);
  prep_b<<<8, 256, 0, stream>>>(b_mu0, b_n0, b_lv0, ml0, b0, 2048);
  prep_b<<<8, 256, 0, stream>>>(b_mu1, b_n1, b_lv1, ml1, b1, 2048);
  prep_b<<<4, 256, 0, stream>>>(b_mu2, b_n2, b_lv2, ml2, b2, 1024);
  cvt_half<<<16384, 256, 0, stream>>>(x, x16);

  gemm_nt<true, true><<<dim3(64, 16), 256, 0, stream>>>(
      x16, W0, b0, h0, 8192, 2048, 2048);
  gemm_nt<true, true><<<dim3(64, 16), 256, 0, stream>>>(
      h0, W1, b1, x16, 8192, 2048, 2048);
  gemm_nt<false, false><<<dim3(64, 8), 256, 0, stream>>>(
      x16, W2, b2, d_out, 8192, 1024, 2048);
  softmax_rows<<<8192, 256, 0, stream>>>((float*)d_out);
}

// Round 2
// 644.979 us; speedup vs baseline: 1.1243x; 1.1243x over previous
//
#include <hip/hip_runtime.h>
#include <hip/hip_fp16.h>

typedef _Float16 half8 __attribute__((ext_vector_type(8)));
typedef _Float16 half4 __attribute__((ext_vector_type(4)));
typedef float floatx4 __attribute__((ext_vector_type(4)));

// async global->LDS, 16B per lane; LDS dest is wave-uniform base + lane*16
#define GLDS16(g, l)                                                           \
  __builtin_amdgcn_global_load_lds(                                            \
      (const __attribute__((address_space(1))) void*)(g),                      \
      (__attribute__((address_space(3))) void*)(l), 16, 0, 0)

// ---------------------------------------------------------------------------
// Effective-weight prep: W_eff = sum_k mw[k]*(mu[k] + exp(0.5*lv[k])*n[k])
// ---------------------------------------------------------------------------
__device__ inline void mix_coeffs(const float* lv, const float* ml,
                                  float* cmu, float* cn) {
  float m0 = ml[0], m1 = ml[1], m2 = ml[2], m3 = ml[3];
  float mx = fmaxf(fmaxf(m0, m1), fmaxf(m2, m3));
  float e0 = __expf(m0 - mx), e1 = __expf(m1 - mx);
  float e2 = __expf(m2 - mx), e3 = __expf(m3 - mx);
  float inv = 1.0f / (e0 + e1 + e2 + e3);
  cmu[0] = e0 * inv; cmu[1] = e1 * inv; cmu[2] = e2 * inv; cmu[3] = e3 * inv;
  cn[0] = cmu[0] * __expf(0.5f * lv[0]);
  cn[1] = cmu[1] * __expf(0.5f * lv[1]);
  cn[2] = cmu[2] * __expf(0.5f * lv[2]);
  cn[3] = cmu[3] * __expf(0.5f * lv[3]);
}

__global__ __launch_bounds__(256) void prep_w(
    const float* __restrict__ mu, const float* __restrict__ nz,
    const float* __restrict__ lv, const float* __restrict__ ml,
    _Float16* __restrict__ out, int count) {
  float cmu[4], cn[4];
  mix_coeffs(lv, ml, cmu, cn);
  long i = ((long)blockIdx.x * 256 + threadIdx.x) * 4;
  if (i >= count) return;
  float rx = 0.f, ry = 0.f, rz = 0.f, rw = 0.f;
#pragma unroll
  for (int k = 0; k < 4; ++k) {
    float4 a = *(const float4*)(mu + (long)k * count + i);
    float4 b = *(const float4*)(nz + (long)k * count + i);
    rx += cmu[k] * a.x + cn[k] * b.x;
    ry += cmu[k] * a.y + cn[k] * b.y;
    rz += cmu[k] * a.z + cn[k] * b.z;
    rw += cmu[k] * a.w + cn[k] * b.w;
  }
  half4 h = {(_Float16)rx, (_Float16)ry, (_Float16)rz, (_Float16)rw};
  *(half4*)(out + i) = h;
}

__global__ __launch_bounds__(256) void prep_b(
    const float* __restrict__ bmu, const float* __restrict__ bn,
    const float* __restrict__ lv, const float* __restrict__ ml,
    float* __restrict__ out, int O) {
  float cmu[4], cn[4];
  mix_coeffs(lv, ml, cmu, cn);
  int i = blockIdx.x * 256 + threadIdx.x;
  if (i >= O) return;
  float r = 0.f;
#pragma unroll
  for (int k = 0; k < 4; ++k)
    r += cmu[k] * bmu[k * O + i] + cn[k] * bn[k * O + i];
  out[i] = r;
}

__global__ __launch_bounds__(256) void cvt_half(
    const float* __restrict__ in, _Float16* __restrict__ out) {
  long i = ((long)blockIdx.x * 256 + threadIdx.x) * 4;
  float4 v = *(const float4*)(in + i);
  half4 h = {(_Float16)v.x, (_Float16)v.y, (_Float16)v.z, (_Float16)v.w};
  *(half4*)(out + i) = h;
}

// ---------------------------------------------------------------------------
// GEMM: C[M,N] = act(A[M,K] * B[N,K]^T + bias), A/B fp16, 128x128 tile, BK=64
// 4 waves in 2x2, each wave 4x4 grid of 16x16x32 fp16 MFMA tiles.
//
// LDS layout: row-major 128x64 fp16 tiles (slot p -> mt=p>>7, m=(p>>3)&15,
// c=p&7; granule byte offset p*16). Each slot holds the XOR-swizzled global
// granule col gc = c ^ (m&7):
//  - staging (GLDS, lane-linear dest): 8 consecutive lanes cover one row's 8
//    granules (permuted) = one contiguous 128B segment -> fully coalesced.
//  - compute ds_read_b128: lane l reads (m=l&15, q=s*4+(l>>4)) at swizzled
//    col (s*4+q)^(m&7) -> 2-way bank aliasing only (free per m136).
// ---------------------------------------------------------------------------
template <bool RELU, bool OUT_HALF>
__global__ __launch_bounds__(256) void gemm_nt(
    const _Float16* __restrict__ A, const _Float16* __restrict__ B,
    const float* __restrict__ bias, void* __restrict__ Cout,
    int M, int N, int K) {
  __shared__ _Float16 sA[128 * 64];
  __shared__ _Float16 sB[128 * 64];

  const int t = threadIdx.x;
  const int l = t & 63;
  const int w = t >> 6;
  const int wr = w >> 1;   // wave row 0..1 (64 rows each)
  const int wc = w & 1;    // wave col 0..1
  const long rowBlock = (long)blockIdx.x * 128;
  const long colBlock = (long)blockIdx.y * 128;

  floatx4 acc[4][4] = {};

  // per-thread staging source pointers (4 granules for A, 4 for B)
  const _Float16* ga[4];
  const _Float16* gb[4];
#pragma unroll
  for (int j = 0; j < 4; ++j) {
    int p = j * 256 + t;          // granule slot 0..1023 (row-major LDS)
    int c = p & 7;                // col granule within row (16B each)
    int m = (p >> 3) & 15;        // row within 16-row tile
    int mt = p >> 7;              // 16-row tile 0..7
    int gc = c ^ (m & 7);         // XOR-swizzled global column granule
    ga[j] = A + (rowBlock + mt * 16 + m) * (long)K + gc * 8;
    gb[j] = B + (colBlock + mt * 16 + m) * (long)K + gc * 8;
  }
  char* stA = (char*)sA + w * 1024;  // wave-uniform LDS staging base
  char* stB = (char*)sB + w * 1024;

  const int mrow = l & 15;           // fragment row
  const int q = l >> 4;              // fragment k-quad 0..3
  const int msw = mrow & 7;          // swizzle key

  for (int k0 = 0; k0 < K; k0 += 64) {
#pragma unroll
    for (int j = 0; j < 4; ++j) {
      GLDS16(ga[j] + k0, stA + j * 4096);
      GLDS16(gb[j] + k0, stB + j * 4096);
    }
    __syncthreads();  // drains vmcnt (compiler emits waitcnt before barrier)
#pragma unroll
    for (int s = 0; s < 2; ++s) {  // two K=32 MFMA steps per BK=64
      const int cidx = (s * 4 + q) ^ msw;  // swizzled col granule
      half8 af[4], bf[4];
#pragma unroll
      for (int r = 0; r < 4; ++r)
        af[r] = *(const half8*)((const char*)sA +
                                ((wr * 4 + r) * 2048 + mrow * 128 + cidx * 16));
#pragma unroll
      for (int c = 0; c < 4; ++c)
        bf[c] = *(const half8*)((const char*)sB +
                                ((wc * 4 + c) * 2048 + mrow * 128 + cidx * 16));
#pragma unroll
      for (int r = 0; r < 4; ++r)
#pragma unroll
        for (int c = 0; c < 4; ++c)
          acc[r][c] = __builtin_amdgcn_mfma_f32_16x16x32_f16(
              af[r], bf[c], acc[r][c], 0, 0, 0);
    }
    __syncthreads();
  }

  // epilogue: C/D layout col=lane&15, row=(lane>>4)*4+reg
  const long row0 = rowBlock + wr * 64 + (l >> 4) * 4;
  const long col0 = colBlock + wc * 64 + (l & 15);
  float bv[4];
#pragma unroll
  for (int c = 0; c < 4; ++c) bv[c] = bias[col0 + c * 16];
#pragma unroll
  for (int r = 0; r < 4; ++r) {
#pragma unroll
    for (int c = 0; c < 4; ++c) {
#pragma unroll
      for (int e = 0; e < 4; ++e) {
        float v = acc[r][c][e] + bv[c];
        if (RELU) v = fmaxf(v, 0.0f);
        long row = row0 + r * 16 + e;
        long col = col0 + c * 16;
        if (OUT_HALF)
          ((_Float16*)Cout)[row * N + col] = (_Float16)v;
        else
          ((float*)Cout)[row * N + col] = v;
      }
    }
  }
}

// ---------------------------------------------------------------------------
// Row softmax over N=1024, one block per row, one float4 per thread
// ---------------------------------------------------------------------------
__global__ __launch_bounds__(256) void softmax_rows(float* __restrict__ io) {
  const int N = 1024;
  float* p = io + (long)blockIdx.x * N;
  int t = threadIdx.x;
  int w = t >> 6;
  float4 v = ((const float4*)p)[t];
  float m = fmaxf(fmaxf(v.x, v.y), fmaxf(v.z, v.w));
#pragma unroll
  for (int off = 32; off > 0; off >>= 1) m = fmaxf(m, __shfl_xor(m, off));
  __shared__ float red[8];
  if ((t & 63) == 0) red[w] = m;
  __syncthreads();
  m = fmaxf(fmaxf(red[0], red[1]), fmaxf(red[2], red[3]));
  float4 e;
  e.x = __expf(v.x - m); e.y = __expf(v.y - m);
  e.z = __expf(v.z - m); e.w = __expf(v.w - m);
  float s = e.x + e.y + e.z + e.w;
#pragma unroll
  for (int off = 32; off > 0; off >>= 1) s += __shfl_xor(s, off);
  if ((t & 63) == 0) red[4 + w] = s;
  __syncthreads();
  s = red[4] + red[5] + red[6] + red[7];
  float inv = 1.0f / s;
  float4 o = {e.x * inv, e.y * inv, e.z * inv, e.w * inv};
  ((float4*)p)[t] = o;
}

// ---------------------------------------------------------------------------
extern "C" void kernel_launch(void* const* d_in, const int* in_sizes, int n_in,
                              void* d_out, int out_size, void* d_ws,
                              size_t ws_size, hipStream_t stream) {
  const float* x     = (const float*)d_in[0];
  const float* w_mu0 = (const float*)d_in[1];
  const float* b_mu0 = (const float*)d_in[2];
  const float* w_lv0 = (const float*)d_in[3];
  const float* b_lv0 = (const float*)d_in[4];
  const float* ml0   = (const float*)d_in[5];
  const float* w_n0  = (const float*)d_in[6];
  const float* b_n0  = (const float*)d_in[7];
  const float* w_mu1 = (const float*)d_in[8];
  const float* b_mu1 = (const float*)d_in[9];
  const float* w_lv1 = (const float*)d_in[10];
  const float* b_lv1 = (const float*)d_in[11];
  const float* ml1   = (const float*)d_in[12];
  const float* w_n1  = (const float*)d_in[13];
  const float* b_n1  = (const float*)d_in[14];
  const float* w_mu2 = (const float*)d_in[15];
  const float* b_mu2 = (const float*)d_in[16];
  const float* w_lv2 = (const float*)d_in[17];
  const float* b_lv2 = (const float*)d_in[18];
  const float* ml2   = (const float*)d_in[19];
  const float* w_n2  = (const float*)d_in[20];
  const float* b_n2  = (const float*)d_in[21];

  char* ws = (char*)d_ws;
  _Float16* x16 = (_Float16*)(ws);              // 33,554,432 B (reused as h1)
  _Float16* h0  = (_Float16*)(ws + 33554432);   // 33,554,432 B
  _Float16* W0  = (_Float16*)(ws + 67108864);   //  8,388,608 B
  _Float16* W1  = (_Float16*)(ws + 75497472);   //  8,388,608 B
  _Float16* W2  = (_Float16*)(ws + 83886080);   //  4,194,304 B
  float* b0 = (float*)(ws + 88080384);          //  8 KB
  float* b1 = (float*)(ws + 88088576);          //  8 KB
  float* b2 = (float*)(ws + 88096768);          //  4 KB

  prep_w<<<4096, 256, 0, stream>>>(w_mu0, w_n0, w_lv0, ml0, W0, 2048 * 2048);
  prep_w<<<4096, 256, 0, stream>>>(w_mu1, w_n1, w_lv1, ml1, W1, 2048 * 2048);
  prep_w<<<2048, 256, 0, stream>>>(w_mu2, w_n2, w_lv2, ml2, W2, 1024 * 2048);
  prep_b<<<8, 256, 0, stream>>>(b_mu0, b_n0, b_lv0, ml0, b0, 2048);
  prep_b<<<8, 256, 0, stream>>>(b_mu1, b_n1, b_lv1, ml1, b1, 2048);
  prep_b<<<4, 256, 0, stream>>>(b_mu2, b_n2, b_lv2, ml2, b2, 1024);
  cvt_half<<<16384, 256, 0, stream>>>(x, x16);

  gemm_nt<true, true><<<dim3(64, 16), 256, 0, stream>>>(
      x16, W0, b0, h0, 8192, 2048, 2048);
  gemm_nt<true, true><<<dim3(64, 16), 256, 0, stream>>>(
      h0, W1, b1, x16, 8192, 2048, 2048);
  gemm_nt<false, false><<<dim3(64, 8), 256, 0, stream>>>(
      x16, W2, b2, d_out, 8192, 1024, 2048);
  softmax_rows<<<8192, 256, 0, stream>>>((float*)d_out);
}

// Round 3
// 590.689 us; speedup vs baseline: 1.2276x; 1.0919x over previous
//
#include <hip/hip_runtime.h>
#include <hip/hip_fp16.h>

typedef _Float16 half8 __attribute__((ext_vector_type(8)));
typedef _Float16 half4 __attribute__((ext_vector_type(4)));
typedef float floatx16 __attribute__((ext_vector_type(16)));

// async global->LDS, 16B per lane; LDS dest is wave-uniform base + lane*16
#define GLDS16(g, l)                                                           \
  __builtin_amdgcn_global_load_lds(                                            \
      (const __attribute__((address_space(1))) void*)(g),                      \
      (__attribute__((address_space(3))) void*)(l), 16, 0, 0)

// ---------------------------------------------------------------------------
// Fused prep: W_eff = sum_k mw[k]*(mu[k]+exp(0.5*lv[k])*n[k]) (fp16 out),
// bias_eff (fp32), and x fp32->fp16 cvt — all in ONE launch to avoid
// inter-kernel drain bubbles.
// ---------------------------------------------------------------------------
__device__ inline void mix_coeffs(const float* lv, const float* ml,
                                  float* cmu, float* cn) {
  float m0 = ml[0], m1 = ml[1], m2 = ml[2], m3 = ml[3];
  float mx = fmaxf(fmaxf(m0, m1), fmaxf(m2, m3));
  float e0 = __expf(m0 - mx), e1 = __expf(m1 - mx);
  float e2 = __expf(m2 - mx), e3 = __expf(m3 - mx);
  float inv = 1.0f / (e0 + e1 + e2 + e3);
  cmu[0] = e0 * inv; cmu[1] = e1 * inv; cmu[2] = e2 * inv; cmu[3] = e3 * inv;
  cn[0] = cmu[0] * __expf(0.5f * lv[0]);
  cn[1] = cmu[1] * __expf(0.5f * lv[1]);
  cn[2] = cmu[2] * __expf(0.5f * lv[2]);
  cn[3] = cmu[3] * __expf(0.5f * lv[3]);
}

__device__ inline void do_prep_w(const float* __restrict__ mu,
                                 const float* __restrict__ nz,
                                 const float* lv, const float* ml,
                                 _Float16* __restrict__ out, int count,
                                 int bid) {
  float cmu[4], cn[4];
  mix_coeffs(lv, ml, cmu, cn);
  long i = ((long)bid * 256 + threadIdx.x) * 4;
  float rx = 0.f, ry = 0.f, rz = 0.f, rw = 0.f;
#pragma unroll
  for (int k = 0; k < 4; ++k) {
    float4 a = *(const float4*)(mu + (long)k * count + i);
    float4 b = *(const float4*)(nz + (long)k * count + i);
    rx += cmu[k] * a.x + cn[k] * b.x;
    ry += cmu[k] * a.y + cn[k] * b.y;
    rz += cmu[k] * a.z + cn[k] * b.z;
    rw += cmu[k] * a.w + cn[k] * b.w;
  }
  half4 h = {(_Float16)rx, (_Float16)ry, (_Float16)rz, (_Float16)rw};
  *(half4*)(out + i) = h;
}

__device__ inline void do_prep_b(const float* __restrict__ bmu,
                                 const float* __restrict__ bn,
                                 const float* lv, const float* ml,
                                 float* __restrict__ out, int O, int bid) {
  float cmu[4], cn[4];
  mix_coeffs(lv, ml, cmu, cn);
  int i = bid * 256 + threadIdx.x;
  if (i >= O) return;
  float r = 0.f;
#pragma unroll
  for (int k = 0; k < 4; ++k)
    r += cmu[k] * bmu[k * O + i] + cn[k] * bn[k * O + i];
  out[i] = r;
}

__device__ inline void do_cvt(const float* __restrict__ in,
                              _Float16* __restrict__ out, int bid) {
  long i = ((long)bid * 256 + threadIdx.x) * 4;
  float4 v = *(const float4*)(in + i);
  half4 h = {(_Float16)v.x, (_Float16)v.y, (_Float16)v.z, (_Float16)v.w};
  *(half4*)(out + i) = h;
}

struct PrepArgs {
  const float* x; _Float16* x16;
  const float* wmu0; const float* wn0; const float* wlv0; const float* ml0; _Float16* W0;
  const float* wmu1; const float* wn1; const float* wlv1; const float* ml1; _Float16* W1;
  const float* wmu2; const float* wn2; const float* wlv2; const float* ml2; _Float16* W2;
  const float* bmu0; const float* bn0; const float* blv0; float* b0;
  const float* bmu1; const float* bn1; const float* blv1; float* b1;
  const float* bmu2; const float* bn2; const float* blv2; float* b2;
};

// grid = 16384 (cvt) + 4096 (W0) + 4096 (W1) + 2048 (W2) + 8 + 8 + 4 = 26644
__global__ __launch_bounds__(256) void prep_all(PrepArgs a) {
  int b = blockIdx.x;
  if (b < 16384) { do_cvt(a.x, a.x16, b); return; }
  b -= 16384;
  if (b < 4096) { do_prep_w(a.wmu0, a.wn0, a.wlv0, a.ml0, a.W0, 2048 * 2048, b); return; }
  b -= 4096;
  if (b < 4096) { do_prep_w(a.wmu1, a.wn1, a.wlv1, a.ml1, a.W1, 2048 * 2048, b); return; }
  b -= 4096;
  if (b < 2048) { do_prep_w(a.wmu2, a.wn2, a.wlv2, a.ml2, a.W2, 1024 * 2048, b); return; }
  b -= 2048;
  if (b < 8) { do_prep_b(a.bmu0, a.bn0, a.blv0, a.ml0, a.b0, 2048, b); return; }
  b -= 8;
  if (b < 8) { do_prep_b(a.bmu1, a.bn1, a.blv1, a.ml1, a.b1, 2048, b); return; }
  b -= 8;
  do_prep_b(a.bmu2, a.bn2, a.blv2, a.ml2, a.b2, 1024, b);
}

// ---------------------------------------------------------------------------
// GEMM: C[M,N] = act(A[M,K] * B[N,K]^T + bias), fp16 in, 32x32x16 MFMA.
// Block = 128 x (CT*64), BK=64, 4 waves in 2x2; wave tile = 64 x (CT*32)
// = 2 x CT grid of 32x32 tiles -> acc[2][CT] of floatx16.
//
// LDS: row-major rows of 8 granules (16B each, BK=64 fp16 = 128B/row) with
// XOR swizzle: LDS(r,pos) holds global granule gc = pos ^ (r&7).
//  - staging GLDS (lane-linear dest): 8 lanes/row read one contiguous 128B
//    segment (permuted within) -> fully coalesced.
//  - fragment read (lane l: row=l&31, granule g=s*2+(l>>5)): pos=g^(r&7);
//    each 8-lane group covers all 32 banks once -> b128 minimum, no excess
//    conflicts (verified 0 in R2 with the same swizzle).
// A-fragment layout (32x32x16): lane holds A[m=l&31][k=(l>>5)*8+j], j=0..7.
// C/D layout (m74/m101): col=lane&31, row=(reg&3)+8*(reg>>2)+4*(lane>>5).
// ---------------------------------------------------------------------------
template <int CT, bool RELU, bool OUT_HALF>
__global__ __launch_bounds__(256, 2) void gemm_nt(
    const _Float16* __restrict__ A, const _Float16* __restrict__ B,
    const float* __restrict__ bias, void* __restrict__ Cout,
    int M, int N, int K) {
  constexpr int BN = CT * 64;
  __shared__ _Float16 sA[128 * 64];
  __shared__ _Float16 sB[BN * 64];

  const int t = threadIdx.x;
  const int l = t & 63;
  const int w = t >> 6;
  const int wr = w >> 1;   // wave row 0..1 (64 rows each)
  const int wc = w & 1;    // wave col 0..1 (CT*32 cols each)
  const long rowBlock = (long)blockIdx.x * 128;
  const long colBlock = (long)blockIdx.y * BN;

  floatx16 acc[2][CT] = {};

  // staging source pointers: A needs 4 GLDS/thread, B needs 2*CT
  const _Float16* ga[4];
  const _Float16* gb[2 * CT];
#pragma unroll
  for (int j = 0; j < 4; ++j) {
    int p = j * 256 + t;
    int r = p >> 3, pos = p & 7;
    int gc = pos ^ (r & 7);
    ga[j] = A + (rowBlock + r) * (long)K + gc * 8;
  }
#pragma unroll
  for (int j = 0; j < 2 * CT; ++j) {
    int p = j * 256 + t;
    int r = p >> 3, pos = p & 7;
    int gc = pos ^ (r & 7);
    gb[j] = B + (colBlock + r) * (long)K + gc * 8;
  }
  char* stA = (char*)sA + w * 1024;  // wave-uniform LDS staging bases
  char* stB = (char*)sB + w * 1024;

  const int rm = l & 31;   // row within 32-tile
  const int kh = l >> 5;   // k-half
  const int sw = rm & 7;   // swizzle key

  for (int k0 = 0; k0 < K; k0 += 64) {
#pragma unroll
    for (int j = 0; j < 4; ++j) GLDS16(ga[j] + k0, stA + j * 4096);
#pragma unroll
    for (int j = 0; j < 2 * CT; ++j) GLDS16(gb[j] + k0, stB + j * 4096);
    __syncthreads();
#pragma unroll
    for (int s = 0; s < 4; ++s) {  // four K=16 MFMA steps per BK=64
      const int pos = (s * 2 + kh) ^ sw;
      half8 af[2], bf[CT];
#pragma unroll
      for (int rt = 0; rt < 2; ++rt)
        af[rt] = *(const half8*)((const char*)sA +
                                 ((wr * 64 + rt * 32 + rm) * 128 + pos * 16));
#pragma unroll
      for (int ct = 0; ct < CT; ++ct)
        bf[ct] = *(const half8*)((const char*)sB +
                                 ((wc * (CT * 32) + ct * 32 + rm) * 128 + pos * 16));
#pragma unroll
      for (int rt = 0; rt < 2; ++rt)
#pragma unroll
        for (int ct = 0; ct < CT; ++ct)
          acc[rt][ct] = __builtin_amdgcn_mfma_f32_32x32x16_f16(
              af[rt], bf[ct], acc[rt][ct], 0, 0, 0);
    }
    __syncthreads();
  }

  // epilogue
  const int cl = l & 31;
  const int rh = (l >> 5) * 4;
#pragma unroll
  for (int rt = 0; rt < 2; ++rt) {
#pragma unroll
    for (int ct = 0; ct < CT; ++ct) {
      const long colg = colBlock + wc * (CT * 32) + ct * 32 + cl;
      const float bv = bias[colg];
#pragma unroll
      for (int reg = 0; reg < 16; ++reg) {
        const int rowin = (reg & 3) + 8 * (reg >> 2) + rh;
        const long rowg = rowBlock + wr * 64 + rt * 32 + rowin;
        float v = acc[rt][ct][reg] + bv;
        if (RELU) v = fmaxf(v, 0.0f);
        if (OUT_HALF)
          ((_Float16*)Cout)[rowg * N + colg] = (_Float16)v;
        else
          ((float*)Cout)[rowg * N + colg] = v;
      }
    }
  }
}

// ---------------------------------------------------------------------------
// Row softmax over N=1024, one block per row, one float4 per thread
// ---------------------------------------------------------------------------
__global__ __launch_bounds__(256) void softmax_rows(float* __restrict__ io) {
  const int N = 1024;
  float* p = io + (long)blockIdx.x * N;
  int t = threadIdx.x;
  int w = t >> 6;
  float4 v = ((const float4*)p)[t];
  float m = fmaxf(fmaxf(v.x, v.y), fmaxf(v.z, v.w));
#pragma unroll
  for (int off = 32; off > 0; off >>= 1) m = fmaxf(m, __shfl_xor(m, off));
  __shared__ float red[8];
  if ((t & 63) == 0) red[w] = m;
  __syncthreads();
  m = fmaxf(fmaxf(red[0], red[1]), fmaxf(red[2], red[3]));
  float4 e;
  e.x = __expf(v.x - m); e.y = __expf(v.y - m);
  e.z = __expf(v.z - m); e.w = __expf(v.w - m);
  float s = e.x + e.y + e.z + e.w;
#pragma unroll
  for (int off = 32; off > 0; off >>= 1) s += __shfl_xor(s, off);
  if ((t & 63) == 0) red[4 + w] = s;
  __syncthreads();
  s = red[4] + red[5] + red[6] + red[7];
  float inv = 1.0f / s;
  float4 o = {e.x * inv, e.y * inv, e.z * inv, e.w * inv};
  ((float4*)p)[t] = o;
}

// ---------------------------------------------------------------------------
extern "C" void kernel_launch(void* const* d_in, const int* in_sizes, int n_in,
                              void* d_out, int out_size, void* d_ws,
                              size_t ws_size, hipStream_t stream) {
  char* ws = (char*)d_ws;
  _Float16* x16 = (_Float16*)(ws);              // 33,554,432 B (reused as h1)
  _Float16* h0  = (_Float16*)(ws + 33554432);   // 33,554,432 B
  _Float16* W0  = (_Float16*)(ws + 67108864);   //  8,388,608 B
  _Float16* W1  = (_Float16*)(ws + 75497472);   //  8,388,608 B
  _Float16* W2  = (_Float16*)(ws + 83886080);   //  4,194,304 B
  float* b0 = (float*)(ws + 88080384);          //  8 KB
  float* b1 = (float*)(ws + 88088576);          //  8 KB
  float* b2 = (float*)(ws + 88096768);          //  4 KB

  PrepArgs a;
  a.x = (const float*)d_in[0]; a.x16 = x16;
  a.wmu0 = (const float*)d_in[1];  a.bmu0 = (const float*)d_in[2];
  a.wlv0 = (const float*)d_in[3];  a.blv0 = (const float*)d_in[4];
  a.ml0  = (const float*)d_in[5];
  a.wn0  = (const float*)d_in[6];  a.bn0  = (const float*)d_in[7];
  a.wmu1 = (const float*)d_in[8];  a.bmu1 = (const float*)d_in[9];
  a.wlv1 = (const float*)d_in[10]; a.blv1 = (const float*)d_in[11];
  a.ml1  = (const float*)d_in[12];
  a.wn1  = (const float*)d_in[13]; a.bn1  = (const float*)d_in[14];
  a.wmu2 = (const float*)d_in[15]; a.bmu2 = (const float*)d_in[16];
  a.wlv2 = (const float*)d_in[17]; a.blv2 = (const float*)d_in[18];
  a.ml2  = (const float*)d_in[19];
  a.wn2  = (const float*)d_in[20]; a.bn2  = (const float*)d_in[21];
  a.W0 = W0; a.W1 = W1; a.W2 = W2; a.b0 = b0; a.b1 = b1; a.b2 = b2;

  prep_all<<<26644, 256, 0, stream>>>(a);

  gemm_nt<4, true, true><<<dim3(64, 8), 256, 0, stream>>>(
      x16, W0, b0, h0, 8192, 2048, 2048);
  gemm_nt<4, true, true><<<dim3(64, 8), 256, 0, stream>>>(
      h0, W1, b1, x16, 8192, 2048, 2048);
  gemm_nt<2, false, false><<<dim3(64, 8), 256, 0, stream>>>(
      x16, W2, b2, d_out, 8192, 1024, 2048);
  softmax_rows<<<8192, 256, 0, stream>>>((float*)d_out);
}